// Round 13
// baseline (302.689 us; speedup 1.0000x reference)
//
#include <hip/hip_runtime.h>
#include <hip/hip_fp16.h>

// GAT (2 layers, heads=1) + 2-layer MLP head. N=100000, E=3200000, D=128.
// R13: 64-node buckets (1563 blocks, 256 thr) + SORT-ONCE: agg1 counting-sorts
// its bucket and persists the sorted src list + node offsets; agg2 skips the
// sort entirely and streams runs from global. Fixed-capacity regions (no
// histogram kernels); overflow -> full-rescan fallback in both aggs.
// Softmax stabilization uses a GLOBAL upper bound m̄_i = leaky(gmax_asrc + adst_i)
// (valid since leaky_relu is monotone); alpha is mathematically unchanged.

#define NEG 0.2f
#define FSH 6
#define BNODES 64            // nodes per bucket
#define NSBMAX 2048          // >= ceil(100000/64)=1563
#define CAPB 2560            // per-bucket region capacity (mean 2048, +11 sigma)
#define TILE 8192            // edges per csplit block
#define PES 10               // ceil(CAPB/256) register-staged pairs per thread

__device__ __forceinline__ float lrelu(float x) { return x > 0.0f ? x : NEG * x; }

__device__ __forceinline__ unsigned fenc(float f) {
    unsigned u = __float_as_uint(f);
    return (u & 0x80000000u) ? ~u : (u | 0x80000000u);
}
__device__ __forceinline__ float fdec(unsigned e) {
    return (e & 0x80000000u) ? __uint_as_float(e & 0x7FFFFFFFu) : __uint_as_float(~e);
}

// load 4 consecutive halves as float4 (8B load)
__device__ __forceinline__ float4 ldh4(const __half* h, size_t off) {
    uint2 u = *(const uint2*)(h + off);
    __half2 a = *(__half2*)&u.x, b = *(__half2*)&u.y;
    float2 fa = __half22float2(a), fb = __half22float2(b);
    return make_float4(fa.x, fa.y, fb.x, fb.y);
}

// init gmax + per-bucket region cursors (absolute positions)
__global__ __launch_bounds__(256) void k_init(unsigned* g, int* bcur, int NSB) {
    int i = blockIdx.x * 256 + threadIdx.x;
    if (i < NSB) bcur[i * 16] = i * CAPB;
    if (i < 2) g[i] = 0u;
}

// K1: h1 = x @ W1 (128->16) [fp16 out], s1 = h1·a1s, d1 = h1·a1d, gmax1 = max(s1)
__global__ __launch_bounds__(256) void k_gemm1(
    const float* __restrict__ x, const float* __restrict__ W1,
    const float* __restrict__ a1s, const float* __restrict__ a1d,
    __half* __restrict__ h1, float* __restrict__ s1, float* __restrict__ d1,
    unsigned* __restrict__ gmax, int N)
{
    __shared__ float sW[128 * 16];
    __shared__ float sx[64 * 132];
    __shared__ float wm[4];
    int tid = threadIdx.x;
    for (int i = tid; i < 2048; i += 256) sW[i] = W1[i];
    int node0 = blockIdx.x * 64;
    for (int i = tid; i < 64 * 32; i += 256) {
        int row = i >> 5, c4 = i & 31;
        int n = node0 + row;
        float4 v = make_float4(0.f, 0.f, 0.f, 0.f);
        if (n < N) v = ((const float4*)x)[(size_t)n * 32 + c4];
        *(float4*)&sx[row * 132 + c4 * 4] = v;
    }
    __syncthreads();

    int node = node0 + (tid >> 2);
    int grp  = tid & 3;
    const float* xr = &sx[(tid >> 2) * 132];
    float4 acc = make_float4(0.f, 0.f, 0.f, 0.f);
#pragma unroll 8
    for (int j = 0; j < 128; ++j) {
        float xv = xr[j];
        float4 w = *(const float4*)&sW[j * 16 + grp * 4];
        acc.x += xv * w.x; acc.y += xv * w.y; acc.z += xv * w.z; acc.w += xv * w.w;
    }
    float4 as = ((const float4*)a1s)[grp];
    float4 ad = ((const float4*)a1d)[grp];
    float sv = acc.x * as.x + acc.y * as.y + acc.z * as.z + acc.w * as.w;
    float dv = acc.x * ad.x + acc.y * ad.y + acc.z * ad.z + acc.w * ad.w;
    sv += __shfl_xor(sv, 1); sv += __shfl_xor(sv, 2);
    dv += __shfl_xor(dv, 1); dv += __shfl_xor(dv, 2);
    if (node < N) {
        __half2 p0 = __floats2half2_rn(acc.x, acc.y);
        __half2 p1 = __floats2half2_rn(acc.z, acc.w);
        uint2 u; u.x = *(unsigned*)&p0; u.y = *(unsigned*)&p1;
        *(uint2*)&h1[(size_t)node * 16 + grp * 4] = u;
        if (grp == 0) { s1[node] = sv; d1[node] = dv; }
    }
    float m = (node < N) ? sv : -3.4e38f;
#pragma unroll
    for (int off = 32; off >= 1; off >>= 1) m = fmaxf(m, __shfl_xor(m, off));
    if ((tid & 63) == 0) wm[tid >> 6] = m;
    __syncthreads();
    if (tid == 0) {
        float b = fmaxf(fmaxf(wm[0], wm[1]), fmaxf(wm[2], wm[3]));
        atomicMax(gmax, fenc(b));
    }
}

// split: LDS-sort a tile of 8192 edges by 64-node bucket, flush run-granular
// into fixed per-bucket regions; elements past a region's limit are dropped
// (bucket flagged by cursor > limit; agg rescans such buckets from the source).
__global__ __launch_bounds__(512) void k_csplit(
    const int* __restrict__ esrc, const int* __restrict__ edst,
    int* __restrict__ bcur, unsigned* __restrict__ pairs, int E, int NSB)
{
    __shared__ unsigned lsrt[TILE];
    __shared__ int lhist[NSBMAX];        // counts -> cursors
    __shared__ int lofs[NSBMAX];         // exclusive run starts
    __shared__ int gbase[NSBMAX];
    __shared__ int wsum[8];
    int tid = threadIdx.x;
    int base = blockIdx.x * TILE;
    int tcnt = min(TILE, E - base);
    for (int i = tid; i < NSB; i += 512) lhist[i] = 0;
    __syncthreads();
    for (int i = tid; i < tcnt; i += 512)
        atomicAdd(&lhist[edst[base + i] >> FSH], 1);
    __syncthreads();
    // 4-entry-per-thread scan (covers up to 2048 buckets)
    int i0 = 4 * tid;
    int c0 = (i0 + 0 < NSB) ? lhist[i0 + 0] : 0;
    int c1 = (i0 + 1 < NSB) ? lhist[i0 + 1] : 0;
    int c2 = (i0 + 2 < NSB) ? lhist[i0 + 2] : 0;
    int c3 = (i0 + 3 < NSB) ? lhist[i0 + 3] : 0;
    int s = c0 + c1 + c2 + c3, pfx = s;
#pragma unroll
    for (int off = 1; off < 64; off <<= 1) {
        int t = __shfl_up(pfx, off, 64);
        if ((tid & 63) >= off) pfx += t;
    }
    if ((tid & 63) == 63) wsum[tid >> 6] = pfx;
    __syncthreads();
    int carry = 0;
    for (int w = 0; w < (tid >> 6); ++w) carry += wsum[w];
    int excl = pfx + carry - s;
    int cc[4] = { c0, c1, c2, c3 };
    for (int u = 0; u < 4; ++u) {
        int i = i0 + u;
        if (i < NSB) {
            lofs[i] = excl;
            gbase[i] = cc[u] ? atomicAdd(&bcur[i * 16], cc[u]) : 0;
            excl += cc[u];
        }
    }
    __syncthreads();
    for (int i = tid; i < NSB; i += 512) lhist[i] = lofs[i];  // cursors
    __syncthreads();
    for (int i = tid; i < tcnt; i += 512) {
        int e = base + i;
        int d = edst[e], srcv = esrc[e];
        int pos = atomicAdd(&lhist[d >> FSH], 1);
        lsrt[pos] = ((unsigned)(d & (BNODES - 1)) << 17) | (unsigned)srcv;
    }
    __syncthreads();
    // flattened flush: binary search run id, coalesced run-contiguous stores
    for (int i = tid; i < tcnt; i += 512) {
        int lo = 0, hi = NSB - 1;
        while (lo < hi) { int mid = (lo + hi + 1) >> 1; if (lofs[mid] <= i) lo = mid; else hi = mid - 1; }
        int gp = gbase[lo] + (i - lofs[lo]);
        if (gp < (lo + 1) * CAPB) pairs[gp] = lsrt[i];
    }
}

// ---- layer-1 agg: sort own region (persist sorted list!) + pipelined gather ----
__global__ __launch_bounds__(256) void k_agg1(
    const int* __restrict__ bcur, unsigned* __restrict__ pairs,
    int* __restrict__ nodeofs,
    const int* __restrict__ esrc, const int* __restrict__ edst,
    const float* __restrict__ s1, const float* __restrict__ d1, const __half* __restrict__ h1,
    const float* __restrict__ b1, const float* __restrict__ W2,
    const float* __restrict__ a2s, const float* __restrict__ a2d,
    __half* __restrict__ h2, float* __restrict__ s2, float* __restrict__ d2,
    const unsigned* __restrict__ gmax1p, unsigned* __restrict__ gmax2, int N, int E)
{
    __shared__ unsigned srt[CAPB];
    __shared__ float accs[BNODES * 17];
    __shared__ int lcnt[BNODES];
    __shared__ int lofs[BNODES + 1];
    __shared__ float dds[BNODES], mbs[BNODES];
    __shared__ float sW[160], sb[16], sas[16], sad[16];
    __shared__ float wm[4];

    int tid = threadIdx.x;
    int fb = blockIdx.x;
    if (tid < 160) sW[tid] = W2[tid];
    if (tid < 16) {
        sb[tid]  = b1[tid];
        sas[tid] = (tid < 10) ? a2s[tid] : 0.f;
        sad[tid] = (tid < 10) ? a2d[tid] : 0.f;
    }
    int node0 = fb << FSH;
    float g0 = fdec(*gmax1p);
    if (tid < BNODES) {
        int n = node0 + tid;
        float dd = (n < N) ? d1[n] : 0.f;
        dds[tid] = dd; mbs[tid] = lrelu(g0 + dd);
        lcnt[tid] = 0;
    }
    __syncthreads();

    int rbase = fb * CAPB;
    int cnt = bcur[fb * 16] - rbase;     // block-uniform; > CAPB means overflow
    int gg = tid >> 2, q = tid & 3;      // 64 groups x 4 lanes, 1 node each

    if (cnt <= CAPB) {
        // count pass with register staging (single global read of pairs)
        unsigned pe[PES];
#pragma unroll
        for (int u = 0; u < PES; ++u) {
            int i = tid + u * 256;
            bool ok = (i < cnt);
            pe[u] = ok ? pairs[rbase + i] : 0u;
            if (ok) atomicAdd(&lcnt[(pe[u] >> 17) & (BNODES - 1)], 1);
        }
        __syncthreads();
        // 64-key scan in wave 0
        if (tid < 64) {
            int c = lcnt[tid], pfx = c;
#pragma unroll
            for (int off = 1; off < 64; off <<= 1) {
                int t = __shfl_up(pfx, off, 64);
                if (tid >= off) pfx += t;
            }
            lofs[tid + 1] = pfx;
            if (tid == 0) lofs[0] = 0;
            lcnt[tid] = pfx - c;         // cursors
        }
        __syncthreads();
        // scatter pass from registers -> dst-sorted srcs
#pragma unroll
        for (int u = 0; u < PES; ++u) {
            int i = tid + u * 256;
            if (i < cnt) {
                unsigned p = pe[u];
                int pos = atomicAdd(&lcnt[(p >> 17) & (BNODES - 1)], 1);
                srt[pos] = p & 0x1FFFF;
            }
        }
        __syncthreads();
        // persist sorted list + offsets for agg2 (region already consumed)
        for (int i = tid; i < cnt; i += 256) pairs[rbase + i] = srt[i];
        if (tid <= BNODES) nodeofs[fb * (BNODES + 1) + tid] = lofs[tid];

        // self-loop init + 8-edge pipelined gather (2 exp/lane, width-4 shfl)
        int n = node0 + gg;
        float4 accv; float den;
        if (n < N) {
            float w = __expf(lrelu(s1[n] + dds[gg]) - mbs[gg]);
            float4 hv = ldh4(h1, (size_t)n * 16 + 4 * q);
            accv = make_float4(w * hv.x, w * hv.y, w * hv.z, w * hv.w);
            den = w;
        } else { accv = make_float4(0.f, 0.f, 0.f, 0.f); den = 0.f; }
        {
            float dd = dds[gg], mb = mbs[gg];
            int j = lofs[gg], j1 = lofs[gg + 1];
            for (; j + 8 <= j1; j += 8) {
                int e0 = srt[j],     e1 = srt[j + 1], e2 = srt[j + 2], e3 = srt[j + 3];
                int e4 = srt[j + 4], e5 = srt[j + 5], e6 = srt[j + 6], e7 = srt[j + 7];
                int eqa = srt[j + q], eqb = srt[j + 4 + q];
                float4 H0 = ldh4(h1, (size_t)e0 * 16 + 4 * q);
                float4 H1 = ldh4(h1, (size_t)e1 * 16 + 4 * q);
                float4 H2 = ldh4(h1, (size_t)e2 * 16 + 4 * q);
                float4 H3 = ldh4(h1, (size_t)e3 * 16 + 4 * q);
                float4 H4 = ldh4(h1, (size_t)e4 * 16 + 4 * q);
                float4 H5 = ldh4(h1, (size_t)e5 * 16 + 4 * q);
                float4 H6 = ldh4(h1, (size_t)e6 * 16 + 4 * q);
                float4 H7 = ldh4(h1, (size_t)e7 * 16 + 4 * q);
                float sA = s1[eqa], sB = s1[eqb];
                float wA = __expf(lrelu(sA + dd) - mb);
                float wB = __expf(lrelu(sB + dd) - mb);
                float w0 = __shfl(wA, 0, 4), w1 = __shfl(wA, 1, 4);
                float w2 = __shfl(wA, 2, 4), w3 = __shfl(wA, 3, 4);
                float w4 = __shfl(wB, 0, 4), w5 = __shfl(wB, 1, 4);
                float w6 = __shfl(wB, 2, 4), w7 = __shfl(wB, 3, 4);
                accv.x += w0 * H0.x + w1 * H1.x + w2 * H2.x + w3 * H3.x
                        + w4 * H4.x + w5 * H5.x + w6 * H6.x + w7 * H7.x;
                accv.y += w0 * H0.y + w1 * H1.y + w2 * H2.y + w3 * H3.y
                        + w4 * H4.y + w5 * H5.y + w6 * H6.y + w7 * H7.y;
                accv.z += w0 * H0.z + w1 * H1.z + w2 * H2.z + w3 * H3.z
                        + w4 * H4.z + w5 * H5.z + w6 * H6.z + w7 * H7.z;
                accv.w += w0 * H0.w + w1 * H1.w + w2 * H2.w + w3 * H3.w
                        + w4 * H4.w + w5 * H5.w + w6 * H6.w + w7 * H7.w;
                den += ((w0 + w1) + (w2 + w3)) + ((w4 + w5) + (w6 + w7));
            }
            if (j + 4 <= j1) {
                int e0 = srt[j], e1 = srt[j + 1], e2 = srt[j + 2], e3 = srt[j + 3];
                float4 H0 = ldh4(h1, (size_t)e0 * 16 + 4 * q);
                float4 H1 = ldh4(h1, (size_t)e1 * 16 + 4 * q);
                float4 H2 = ldh4(h1, (size_t)e2 * 16 + 4 * q);
                float4 H3 = ldh4(h1, (size_t)e3 * 16 + 4 * q);
                int eq = srt[j + q];
                float wq = __expf(lrelu(s1[eq] + dd) - mb);
                float w0 = __shfl(wq, 0, 4), w1 = __shfl(wq, 1, 4);
                float w2 = __shfl(wq, 2, 4), w3 = __shfl(wq, 3, 4);
                accv.x += w0 * H0.x + w1 * H1.x + w2 * H2.x + w3 * H3.x;
                accv.y += w0 * H0.y + w1 * H1.y + w2 * H2.y + w3 * H3.y;
                accv.z += w0 * H0.z + w1 * H1.z + w2 * H2.z + w3 * H3.z;
                accv.w += w0 * H0.w + w1 * H1.w + w2 * H2.w + w3 * H3.w;
                den += (w0 + w1) + (w2 + w3);
                j += 4;
            }
            for (; j < j1; ++j) {
                int e0 = srt[j];
                float w0 = __expf(lrelu(s1[e0] + dd) - mb);
                float4 H0 = ldh4(h1, (size_t)e0 * 16 + 4 * q);
                accv.x += w0 * H0.x; accv.y += w0 * H0.y;
                accv.z += w0 * H0.z; accv.w += w0 * H0.w;
                den += w0;
            }
        }
        // stage accumulators to LDS (stride-17 rows)
        accs[gg * 17 + 4 * q + 0] = accv.x;
        accs[gg * 17 + 4 * q + 1] = accv.y;
        accs[gg * 17 + 4 * q + 2] = accv.z;
        accs[gg * 17 + 4 * q + 3] = accv.w;
        if (q == 0) accs[gg * 17 + 16] = den;
        __syncthreads();
    } else {
        // overflow: region incomplete -> full rescan of source edges (never-path)
        for (int i = tid; i < BNODES * 17; i += 256) accs[i] = 0.f;
        __syncthreads();
        if (tid < BNODES) {
            int n = node0 + tid;
            if (n < N) {
                float w = __expf(lrelu(s1[n] + dds[tid]) - mbs[tid]);
#pragma unroll
                for (int t = 0; t < 16; ++t)
                    accs[tid * 17 + t] = w * __half2float(h1[(size_t)n * 16 + t]);
                accs[tid * 17 + 16] = w;
            }
        }
        __syncthreads();
        for (int i = tid; i < E; i += 256) {
            int d = edst[i];
            if ((d >> FSH) != fb) continue;
            int nl = d & (BNODES - 1), src = esrc[i];
            float w = __expf(lrelu(s1[src] + dds[nl]) - mbs[nl]);
#pragma unroll
            for (int t = 0; t < 16; ++t)
                atomicAdd(&accs[nl * 17 + t], w * __half2float(h1[(size_t)src * 16 + t]));
            atomicAdd(&accs[nl * 17 + 16], w);
        }
        __syncthreads();
    }

    // epilogue: 16 groups of 16 lanes, 4 nodes each
    int g = tid >> 4, k = tid & 15;
    float sval = -3.4e38f;
#pragma unroll
    for (int qq = 0; qq < 4; ++qq) {
        int nl = g * 4 + qq, nn = node0 + nl;
        if (nn >= N) continue;           // group-uniform
        float inv = 1.f / accs[nl * 17 + 16];
        float o = fmaxf(accs[nl * 17 + k] * inv + sb[k], 0.f);
        float hh = 0.f;
#pragma unroll
        for (int kk = 0; kk < 16; ++kk) {
            float ov = __shfl(o, kk, 16);
            if (k < 10) hh += ov * sW[kk * 10 + k];
        }
        if (k >= 10) hh = 0.f;
        float ts = hh * sas[k];
        float td = hh * sad[k];
#pragma unroll
        for (int off = 1; off < 16; off <<= 1) {
            ts += __shfl_xor(ts, off, 16);
            td += __shfl_xor(td, off, 16);
        }
        h2[(size_t)nn * 16 + k] = __float2half_rn(hh);  // zero-padded cols 10..15
        if (k == 0) { s2[nn] = ts; d2[nn] = td; }
        sval = fmaxf(sval, ts);
    }
    float m = sval;
#pragma unroll
    for (int off = 32; off >= 1; off >>= 1) m = fmaxf(m, __shfl_xor(m, off));
    if ((tid & 63) == 0) wm[tid >> 6] = m;
    __syncthreads();
    if (tid == 0) {
        float bmx = fmaxf(fmaxf(wm[0], wm[1]), fmaxf(wm[2], wm[3]));
        atomicMax(gmax2, fenc(bmx));
    }
}

// ---- layer-2 agg: NO sort — stream agg1's sorted runs + MLP head -> out ----
__global__ __launch_bounds__(256) void k_agg2(
    const int* __restrict__ bcur, const unsigned* __restrict__ pairs,
    const int* __restrict__ nodeofs,
    const int* __restrict__ esrc, const int* __restrict__ edst,
    const float* __restrict__ s2, const float* __restrict__ d2, const __half* __restrict__ h2,
    const float* __restrict__ b2, const float* __restrict__ Wl1, const float* __restrict__ bl1,
    const float* __restrict__ Wl2, const float* __restrict__ bl2,
    const unsigned* __restrict__ gmax2p, float* __restrict__ out, int N, int E)
{
    __shared__ float accs[BNODES * 17];
    __shared__ float dds[BNODES], mbs[BNODES];
    __shared__ float sW1[100], sb1[16], sW2[16], sb2g[16];
    __shared__ float sbl2;

    int tid = threadIdx.x;
    int fb = blockIdx.x;
    if (tid < 100) sW1[tid] = Wl1[tid];
    if (tid < 16) {
        sb1[tid]  = (tid < 10) ? bl1[tid] : 0.f;
        sW2[tid]  = (tid < 10) ? Wl2[tid] : 0.f;
        sb2g[tid] = (tid < 10) ? b2[tid]  : 0.f;
    }
    if (tid == 0) sbl2 = bl2[0];
    int node0 = fb << FSH;
    float g0 = fdec(*gmax2p);
    if (tid < BNODES) {
        int n = node0 + tid;
        float dd = (n < N) ? d2[n] : 0.f;
        dds[tid] = dd; mbs[tid] = lrelu(g0 + dd);
    }
    __syncthreads();

    int rbase = fb * CAPB;
    int cnt = bcur[fb * 16] - rbase;
    int gg = tid >> 2, q = tid & 3;

    if (cnt <= CAPB) {
        const unsigned* gs = pairs + rbase;   // sorted srcs from agg1
        const int* nof = nodeofs + fb * (BNODES + 1);
        int n = node0 + gg;
        float4 accv; float den;
        if (n < N) {
            float w = __expf(lrelu(s2[n] + dds[gg]) - mbs[gg]);
            float4 hv = ldh4(h2, (size_t)n * 16 + 4 * q);   // zero-padded
            accv = make_float4(w * hv.x, w * hv.y, w * hv.z, w * hv.w);
            den = w;
        } else { accv = make_float4(0.f, 0.f, 0.f, 0.f); den = 0.f; }
        {
            float dd = dds[gg], mb = mbs[gg];
            int j = nof[gg], j1 = nof[gg + 1];
            for (; j + 8 <= j1; j += 8) {
                int e0 = gs[j],     e1 = gs[j + 1], e2 = gs[j + 2], e3 = gs[j + 3];
                int e4 = gs[j + 4], e5 = gs[j + 5], e6 = gs[j + 6], e7 = gs[j + 7];
                int eqa = gs[j + q], eqb = gs[j + 4 + q];
                float4 H0 = ldh4(h2, (size_t)e0 * 16 + 4 * q);
                float4 H1 = ldh4(h2, (size_t)e1 * 16 + 4 * q);
                float4 H2 = ldh4(h2, (size_t)e2 * 16 + 4 * q);
                float4 H3 = ldh4(h2, (size_t)e3 * 16 + 4 * q);
                float4 H4 = ldh4(h2, (size_t)e4 * 16 + 4 * q);
                float4 H5 = ldh4(h2, (size_t)e5 * 16 + 4 * q);
                float4 H6 = ldh4(h2, (size_t)e6 * 16 + 4 * q);
                float4 H7 = ldh4(h2, (size_t)e7 * 16 + 4 * q);
                float sA = s2[eqa], sB = s2[eqb];
                float wA = __expf(lrelu(sA + dd) - mb);
                float wB = __expf(lrelu(sB + dd) - mb);
                float w0 = __shfl(wA, 0, 4), w1 = __shfl(wA, 1, 4);
                float w2 = __shfl(wA, 2, 4), w3 = __shfl(wA, 3, 4);
                float w4 = __shfl(wB, 0, 4), w5 = __shfl(wB, 1, 4);
                float w6 = __shfl(wB, 2, 4), w7 = __shfl(wB, 3, 4);
                accv.x += w0 * H0.x + w1 * H1.x + w2 * H2.x + w3 * H3.x
                        + w4 * H4.x + w5 * H5.x + w6 * H6.x + w7 * H7.x;
                accv.y += w0 * H0.y + w1 * H1.y + w2 * H2.y + w3 * H3.y
                        + w4 * H4.y + w5 * H5.y + w6 * H6.y + w7 * H7.y;
                accv.z += w0 * H0.z + w1 * H1.z + w2 * H2.z + w3 * H3.z
                        + w4 * H4.z + w5 * H5.z + w6 * H6.z + w7 * H7.z;
                accv.w += w0 * H0.w + w1 * H1.w + w2 * H2.w + w3 * H3.w
                        + w4 * H4.w + w5 * H5.w + w6 * H6.w + w7 * H7.w;
                den += ((w0 + w1) + (w2 + w3)) + ((w4 + w5) + (w6 + w7));
            }
            if (j + 4 <= j1) {
                int e0 = gs[j], e1 = gs[j + 1], e2 = gs[j + 2], e3 = gs[j + 3];
                float4 H0 = ldh4(h2, (size_t)e0 * 16 + 4 * q);
                float4 H1 = ldh4(h2, (size_t)e1 * 16 + 4 * q);
                float4 H2 = ldh4(h2, (size_t)e2 * 16 + 4 * q);
                float4 H3 = ldh4(h2, (size_t)e3 * 16 + 4 * q);
                int eq = gs[j + q];
                float wq = __expf(lrelu(s2[eq] + dd) - mb);
                float w0 = __shfl(wq, 0, 4), w1 = __shfl(wq, 1, 4);
                float w2 = __shfl(wq, 2, 4), w3 = __shfl(wq, 3, 4);
                accv.x += w0 * H0.x + w1 * H1.x + w2 * H2.x + w3 * H3.x;
                accv.y += w0 * H0.y + w1 * H1.y + w2 * H2.y + w3 * H3.y;
                accv.z += w0 * H0.z + w1 * H1.z + w2 * H2.z + w3 * H3.z;
                accv.w += w0 * H0.w + w1 * H1.w + w2 * H2.w + w3 * H3.w;
                den += (w0 + w1) + (w2 + w3);
                j += 4;
            }
            for (; j < j1; ++j) {
                int e0 = gs[j];
                float w0 = __expf(lrelu(s2[e0] + dd) - mb);
                float4 H0 = ldh4(h2, (size_t)e0 * 16 + 4 * q);
                accv.x += w0 * H0.x; accv.y += w0 * H0.y;
                accv.z += w0 * H0.z; accv.w += w0 * H0.w;
                den += w0;
            }
        }
        accs[gg * 17 + 4 * q + 0] = accv.x;
        accs[gg * 17 + 4 * q + 1] = accv.y;
        accs[gg * 17 + 4 * q + 2] = accv.z;
        accs[gg * 17 + 4 * q + 3] = accv.w;
        if (q == 0) accs[gg * 17 + 16] = den;
        __syncthreads();
    } else {
        // overflow fallback (same condition as agg1; never-path)
        for (int i = tid; i < BNODES * 17; i += 256) accs[i] = 0.f;
        __syncthreads();
        if (tid < BNODES) {
            int n = node0 + tid;
            if (n < N) {
                float w = __expf(lrelu(s2[n] + dds[tid]) - mbs[tid]);
#pragma unroll
                for (int t = 0; t < 16; ++t)
                    accs[tid * 17 + t] = w * __half2float(h2[(size_t)n * 16 + t]);
                accs[tid * 17 + 16] = w;
            }
        }
        __syncthreads();
        for (int i = tid; i < E; i += 256) {
            int d = edst[i];
            if ((d >> FSH) != fb) continue;
            int nl = d & (BNODES - 1), src = esrc[i];
            float w = __expf(lrelu(s2[src] + dds[nl]) - mbs[nl]);
#pragma unroll
            for (int t = 0; t < 16; ++t)
                atomicAdd(&accs[nl * 17 + t], w * __half2float(h2[(size_t)src * 16 + t]));
            atomicAdd(&accs[nl * 17 + 16], w);
        }
        __syncthreads();
    }

    int g = tid >> 4, k = tid & 15;
    bool fk = k < 10;
#pragma unroll
    for (int qq = 0; qq < 4; ++qq) {
        int nl = g * 4 + qq, nn = node0 + nl;
        if (nn >= N) continue;           // group-uniform
        float inv = 1.f / accs[nl * 17 + 16];
        float o = fk ? accs[nl * 17 + k] * inv + sb2g[k] : 0.f;
        float v = sb1[k];
#pragma unroll
        for (int kk = 0; kk < 10; ++kk) {
            float ov = __shfl(o, kk, 16);
            if (fk) v += ov * sW1[kk * 10 + k];
        }
        float t = fmaxf(v, 0.f);
        float cc = t * sW2[k];           // zero for k>=10
#pragma unroll
        for (int off = 1; off < 16; off <<= 1) cc += __shfl_xor(cc, off, 16);
        if (k == 0) out[nn] = cc + sbl2;
    }
}

extern "C" void kernel_launch(void* const* d_in, const int* in_sizes, int n_in,
                              void* d_out, int out_size, void* d_ws, size_t ws_size,
                              hipStream_t stream)
{
    const float* x   = (const float*)d_in[0];
    const int*   ei  = (const int*)  d_in[1];   // [2][E] int32
    const float* W1  = (const float*)d_in[2];
    const float* a1s = (const float*)d_in[3];
    const float* a1d = (const float*)d_in[4];
    const float* b1  = (const float*)d_in[5];
    const float* W2  = (const float*)d_in[6];
    const float* a2s = (const float*)d_in[7];
    const float* a2d = (const float*)d_in[8];
    const float* b2  = (const float*)d_in[9];
    const float* Wl1 = (const float*)d_in[10];
    const float* bl1 = (const float*)d_in[11];
    const float* Wl2 = (const float*)d_in[12];
    const float* bl2 = (const float*)d_in[13];

    int N = in_sizes[0] / 128;
    int E = in_sizes[1] / 2;
    const int* ei_src = ei;
    const int* ei_dst = ei + E;
    int NSB = (N + BNODES - 1) >> FSH;       // 1563 buckets (<= NSBMAX)

    size_t Np = ((size_t)N + 3) & ~(size_t)3;
    size_t need_bytes = (16 + Np * 20) * 4 + (size_t)NSB * 16 * 4
                      + (size_t)NSB * CAPB * 4 + (size_t)NSB * (BNODES + 1) * 4;
    if (ws_size < need_bytes) return;  // degrade to wrong-answer, never fault

    float*    ws    = (float*)d_ws;
    unsigned* gmax1 = (unsigned*)d_ws;       // [0]
    unsigned* gmax2 = gmax1 + 1;             // [1]
    __half* h1 = (__half*)(ws + 16);         // Np*16 halves
    float* s1 = ws + 16 + Np * 8;            // Np
    float* d1 = s1 + Np;                     // Np
    __half* h2 = (__half*)(d1 + Np);         // Np*16 halves (cols 10..15 zero)
    float* s2 = (float*)(h2) + Np * 8;       // Np
    float* d2 = s2 + Np;                     // Np
    int* bcur = (int*)(d2 + Np);             // NSB*16 (1 cursor per 64B)
    unsigned* pairs = (unsigned*)(bcur + (size_t)NSB * 16);  // NSB*CAPB
    int* nodeofs = (int*)(pairs + (size_t)NSB * CAPB);       // NSB*(BNODES+1)

    hipLaunchKernelGGL(k_init, dim3((NSB + 255) / 256), dim3(256), 0, stream, gmax1, bcur, NSB);
    hipLaunchKernelGGL(k_gemm1, dim3((N + 63) / 64), dim3(256), 0, stream,
                       x, W1, a1s, a1d, h1, s1, d1, gmax1, N);
    hipLaunchKernelGGL(k_csplit, dim3((E + TILE - 1) / TILE), dim3(512), 0, stream,
                       ei_src, ei_dst, bcur, pairs, E, NSB);
    hipLaunchKernelGGL(k_agg1, dim3(NSB), dim3(256), 0, stream,
                       bcur, pairs, nodeofs, ei_src, ei_dst, s1, d1, h1, b1, W2, a2s, a2d,
                       h2, s2, d2, gmax1, gmax2, N, E);
    hipLaunchKernelGGL(k_agg2, dim3(NSB), dim3(256), 0, stream,
                       bcur, pairs, nodeofs, ei_src, ei_dst, s2, d2, h2, b2, Wl1, bl1, Wl2, bl2,
                       gmax2, (float*)d_out, N, E);
}

// Round 14
// 288.076 us; speedup vs baseline: 1.0507x; 1.0507x over previous
//
#include <hip/hip_runtime.h>
#include <hip/hip_fp16.h>

// GAT (2 layers, heads=1) + 2-layer MLP head. N=100000, E=3200000, D=128.
// R14: R12's proven 128-node-bucket split (runs ~42B, csplit ~45us) + R13's
// sort-once (agg1 persists sorted srcs + node offsets; agg2 streams, no sort).
// Fixed-capacity regions; overflow -> full-rescan fallback in both aggs.
// Softmax stabilization uses a GLOBAL upper bound m̄_i = leaky(gmax_asrc + adst_i)
// (valid since leaky_relu is monotone); alpha is mathematically unchanged.

#define NEG 0.2f
#define FSH 7
#define BNODES 128           // nodes per bucket
#define NSBMAX 1024          // >= ceil(100000/128)=782
#define CAPB 4608            // per-bucket region capacity (mean 4096, +8 sigma)
#define TILE 8192            // edges per csplit block
#define PES 9                // ceil(CAPB/512) register-staged pairs per thread

__device__ __forceinline__ float lrelu(float x) { return x > 0.0f ? x : NEG * x; }

__device__ __forceinline__ unsigned fenc(float f) {
    unsigned u = __float_as_uint(f);
    return (u & 0x80000000u) ? ~u : (u | 0x80000000u);
}
__device__ __forceinline__ float fdec(unsigned e) {
    return (e & 0x80000000u) ? __uint_as_float(e & 0x7FFFFFFFu) : __uint_as_float(~e);
}

// load 4 consecutive halves as float4 (8B load)
__device__ __forceinline__ float4 ldh4(const __half* h, size_t off) {
    uint2 u = *(const uint2*)(h + off);
    __half2 a = *(__half2*)&u.x, b = *(__half2*)&u.y;
    float2 fa = __half22float2(a), fb = __half22float2(b);
    return make_float4(fa.x, fa.y, fb.x, fb.y);
}

// init gmax + per-bucket region cursors (absolute positions)
__global__ __launch_bounds__(256) void k_init(unsigned* g, int* bcur, int NSB) {
    int i = blockIdx.x * 256 + threadIdx.x;
    if (i < NSB) bcur[i * 16] = i * CAPB;
    if (i < 2) g[i] = 0u;
}

// K1: h1 = x @ W1 (128->16) [fp16 out], s1 = h1·a1s, d1 = h1·a1d, gmax1 = max(s1)
__global__ __launch_bounds__(256) void k_gemm1(
    const float* __restrict__ x, const float* __restrict__ W1,
    const float* __restrict__ a1s, const float* __restrict__ a1d,
    __half* __restrict__ h1, float* __restrict__ s1, float* __restrict__ d1,
    unsigned* __restrict__ gmax, int N)
{
    __shared__ float sW[128 * 16];
    __shared__ float sx[64 * 132];
    __shared__ float wm[4];
    int tid = threadIdx.x;
    for (int i = tid; i < 2048; i += 256) sW[i] = W1[i];
    int node0 = blockIdx.x * 64;
    for (int i = tid; i < 64 * 32; i += 256) {
        int row = i >> 5, c4 = i & 31;
        int n = node0 + row;
        float4 v = make_float4(0.f, 0.f, 0.f, 0.f);
        if (n < N) v = ((const float4*)x)[(size_t)n * 32 + c4];
        *(float4*)&sx[row * 132 + c4 * 4] = v;
    }
    __syncthreads();

    int node = node0 + (tid >> 2);
    int grp  = tid & 3;
    const float* xr = &sx[(tid >> 2) * 132];
    float4 acc = make_float4(0.f, 0.f, 0.f, 0.f);
#pragma unroll 8
    for (int j = 0; j < 128; ++j) {
        float xv = xr[j];
        float4 w = *(const float4*)&sW[j * 16 + grp * 4];
        acc.x += xv * w.x; acc.y += xv * w.y; acc.z += xv * w.z; acc.w += xv * w.w;
    }
    float4 as = ((const float4*)a1s)[grp];
    float4 ad = ((const float4*)a1d)[grp];
    float sv = acc.x * as.x + acc.y * as.y + acc.z * as.z + acc.w * as.w;
    float dv = acc.x * ad.x + acc.y * ad.y + acc.z * ad.z + acc.w * ad.w;
    sv += __shfl_xor(sv, 1); sv += __shfl_xor(sv, 2);
    dv += __shfl_xor(dv, 1); dv += __shfl_xor(dv, 2);
    if (node < N) {
        __half2 p0 = __floats2half2_rn(acc.x, acc.y);
        __half2 p1 = __floats2half2_rn(acc.z, acc.w);
        uint2 u; u.x = *(unsigned*)&p0; u.y = *(unsigned*)&p1;
        *(uint2*)&h1[(size_t)node * 16 + grp * 4] = u;
        if (grp == 0) { s1[node] = sv; d1[node] = dv; }
    }
    float m = (node < N) ? sv : -3.4e38f;
#pragma unroll
    for (int off = 32; off >= 1; off >>= 1) m = fmaxf(m, __shfl_xor(m, off));
    if ((tid & 63) == 0) wm[tid >> 6] = m;
    __syncthreads();
    if (tid == 0) {
        float b = fmaxf(fmaxf(wm[0], wm[1]), fmaxf(wm[2], wm[3]));
        atomicMax(gmax, fenc(b));
    }
}

// split: LDS-sort a tile of 8192 edges by 128-node bucket, flush run-granular
// into fixed per-bucket regions; elements past a region's limit are dropped
// (bucket flagged by cursor > limit; agg rescans such buckets from the source).
__global__ __launch_bounds__(512) void k_csplit(
    const int* __restrict__ esrc, const int* __restrict__ edst,
    int* __restrict__ bcur, unsigned* __restrict__ pairs, int E, int NSB)
{
    __shared__ unsigned lsrt[TILE];
    __shared__ int lhist[NSBMAX];        // counts -> cursors
    __shared__ int lofs[NSBMAX];         // exclusive run starts
    __shared__ int gbase[NSBMAX];
    __shared__ int wsum[8];
    int tid = threadIdx.x;
    int base = blockIdx.x * TILE;
    int tcnt = min(TILE, E - base);
    for (int i = tid; i < NSB; i += 512) lhist[i] = 0;
    __syncthreads();
    for (int i = tid; i < tcnt; i += 512)
        atomicAdd(&lhist[edst[base + i] >> FSH], 1);
    __syncthreads();
    int i0 = 2 * tid, i1 = i0 + 1;
    int a = (i0 < NSB) ? lhist[i0] : 0;
    int b = (i1 < NSB) ? lhist[i1] : 0;
    int s = a + b, pfx = s;
#pragma unroll
    for (int off = 1; off < 64; off <<= 1) {
        int t = __shfl_up(pfx, off, 64);
        if ((tid & 63) >= off) pfx += t;
    }
    if ((tid & 63) == 63) wsum[tid >> 6] = pfx;
    __syncthreads();
    int carry = 0;
    for (int w = 0; w < (tid >> 6); ++w) carry += wsum[w];
    int excl = pfx + carry - s;
    if (i0 < NSB) {
        lofs[i0] = excl;
        gbase[i0] = a ? atomicAdd(&bcur[i0 * 16], a) : 0;
    }
    if (i1 < NSB) {
        lofs[i1] = excl + a;
        gbase[i1] = b ? atomicAdd(&bcur[i1 * 16], b) : 0;
    }
    __syncthreads();
    if (i0 < NSB) lhist[i0] = lofs[i0];  // cursors
    if (i1 < NSB) lhist[i1] = lofs[i1];
    __syncthreads();
    for (int i = tid; i < tcnt; i += 512) {
        int e = base + i;
        int d = edst[e], srcv = esrc[e];
        int pos = atomicAdd(&lhist[d >> FSH], 1);
        lsrt[pos] = ((unsigned)(d & (BNODES - 1)) << 17) | (unsigned)srcv;
    }
    __syncthreads();
    // flattened flush: binary search run id, coalesced run-contiguous stores
    for (int i = tid; i < tcnt; i += 512) {
        int lo = 0, hi = NSB - 1;
        while (lo < hi) { int mid = (lo + hi + 1) >> 1; if (lofs[mid] <= i) lo = mid; else hi = mid - 1; }
        int gp = gbase[lo] + (i - lofs[lo]);
        if (gp < (lo + 1) * CAPB) pairs[gp] = lsrt[i];
    }
}

// ---- layer-1 agg: sort own region (persist sorted list) + pipelined gather ----
__global__ __launch_bounds__(512) void k_agg1(
    const int* __restrict__ bcur, unsigned* __restrict__ pairs,
    int* __restrict__ nodeofs,
    const int* __restrict__ esrc, const int* __restrict__ edst,
    const float* __restrict__ s1, const float* __restrict__ d1, const __half* __restrict__ h1,
    const float* __restrict__ b1, const float* __restrict__ W2,
    const float* __restrict__ a2s, const float* __restrict__ a2d,
    __half* __restrict__ h2, float* __restrict__ s2, float* __restrict__ d2,
    const unsigned* __restrict__ gmax1p, unsigned* __restrict__ gmax2, int N, int E)
{
    __shared__ unsigned srt[CAPB];
    __shared__ float accs[BNODES * 17];
    __shared__ int lcnt[BNODES];
    __shared__ int lofs[BNODES + 1];
    __shared__ float dds[BNODES], mbs[BNODES];
    __shared__ float sW[160], sb[16], sas[16], sad[16];
    __shared__ int wsum[8];
    __shared__ float wm[8];

    int tid = threadIdx.x;
    int fb = blockIdx.x;
    if (tid < 160) sW[tid] = W2[tid];
    if (tid < 16) {
        sb[tid]  = b1[tid];
        sas[tid] = (tid < 10) ? a2s[tid] : 0.f;
        sad[tid] = (tid < 10) ? a2d[tid] : 0.f;
    }
    int node0 = fb << FSH;
    float g0 = fdec(*gmax1p);
    if (tid < BNODES) {
        int n = node0 + tid;
        float dd = (n < N) ? d1[n] : 0.f;
        dds[tid] = dd; mbs[tid] = lrelu(g0 + dd);
        lcnt[tid] = 0;
    }
    __syncthreads();

    int rbase = fb * CAPB;
    int cnt = bcur[fb * 16] - rbase;     // block-uniform; > CAPB means overflow
    int gg = tid >> 2, q = tid & 3;      // 128 groups x 4 lanes, 1 node each

    if (cnt <= CAPB) {
        // count pass with register staging (single global read of pairs)
        unsigned pe[PES];
#pragma unroll
        for (int u = 0; u < PES; ++u) {
            int i = tid + u * 512;
            bool ok = (i < cnt);
            pe[u] = ok ? pairs[rbase + i] : 0u;
            if (ok) atomicAdd(&lcnt[(pe[u] >> 17) & (BNODES - 1)], 1);
        }
        __syncthreads();
        // 128-key scan (padded to 512 threads)
        int c = (tid < BNODES) ? lcnt[tid] : 0;
        int pfx = c;
#pragma unroll
        for (int off = 1; off < 64; off <<= 1) {
            int t = __shfl_up(pfx, off, 64);
            if ((tid & 63) >= off) pfx += t;
        }
        if ((tid & 63) == 63) wsum[tid >> 6] = pfx;
        __syncthreads();
        int carry = 0;
        for (int w = 0; w < (tid >> 6); ++w) carry += wsum[w];
        pfx += carry;
        if (tid < BNODES) { lofs[tid + 1] = pfx; lcnt[tid] = pfx - c; }
        if (tid == 0) lofs[0] = 0;
        __syncthreads();
        // scatter pass from registers -> dst-sorted srcs
#pragma unroll
        for (int u = 0; u < PES; ++u) {
            int i = tid + u * 512;
            if (i < cnt) {
                unsigned p = pe[u];
                int pos = atomicAdd(&lcnt[(p >> 17) & (BNODES - 1)], 1);
                srt[pos] = p & 0x1FFFF;
            }
        }
        __syncthreads();
        // persist sorted list + offsets for agg2 (region already consumed)
        for (int i = tid; i < cnt; i += 512) pairs[rbase + i] = srt[i];
        if (tid <= BNODES) nodeofs[fb * (BNODES + 1) + tid] = lofs[tid];

        // self-loop init + 8-edge pipelined gather (2 exp/lane, width-4 shfl)
        int n = node0 + gg;
        float4 accv; float den;
        if (n < N) {
            float w = __expf(lrelu(s1[n] + dds[gg]) - mbs[gg]);
            float4 hv = ldh4(h1, (size_t)n * 16 + 4 * q);
            accv = make_float4(w * hv.x, w * hv.y, w * hv.z, w * hv.w);
            den = w;
        } else { accv = make_float4(0.f, 0.f, 0.f, 0.f); den = 0.f; }
        {
            float dd = dds[gg], mb = mbs[gg];
            int j = lofs[gg], j1 = lofs[gg + 1];
            for (; j + 8 <= j1; j += 8) {
                int e0 = srt[j],     e1 = srt[j + 1], e2 = srt[j + 2], e3 = srt[j + 3];
                int e4 = srt[j + 4], e5 = srt[j + 5], e6 = srt[j + 6], e7 = srt[j + 7];
                int eqa = srt[j + q], eqb = srt[j + 4 + q];
                float4 H0 = ldh4(h1, (size_t)e0 * 16 + 4 * q);
                float4 H1 = ldh4(h1, (size_t)e1 * 16 + 4 * q);
                float4 H2 = ldh4(h1, (size_t)e2 * 16 + 4 * q);
                float4 H3 = ldh4(h1, (size_t)e3 * 16 + 4 * q);
                float4 H4 = ldh4(h1, (size_t)e4 * 16 + 4 * q);
                float4 H5 = ldh4(h1, (size_t)e5 * 16 + 4 * q);
                float4 H6 = ldh4(h1, (size_t)e6 * 16 + 4 * q);
                float4 H7 = ldh4(h1, (size_t)e7 * 16 + 4 * q);
                float sA = s1[eqa], sB = s1[eqb];
                float wA = __expf(lrelu(sA + dd) - mb);
                float wB = __expf(lrelu(sB + dd) - mb);
                float w0 = __shfl(wA, 0, 4), w1 = __shfl(wA, 1, 4);
                float w2 = __shfl(wA, 2, 4), w3 = __shfl(wA, 3, 4);
                float w4 = __shfl(wB, 0, 4), w5 = __shfl(wB, 1, 4);
                float w6 = __shfl(wB, 2, 4), w7 = __shfl(wB, 3, 4);
                accv.x += w0 * H0.x + w1 * H1.x + w2 * H2.x + w3 * H3.x
                        + w4 * H4.x + w5 * H5.x + w6 * H6.x + w7 * H7.x;
                accv.y += w0 * H0.y + w1 * H1.y + w2 * H2.y + w3 * H3.y
                        + w4 * H4.y + w5 * H5.y + w6 * H6.y + w7 * H7.y;
                accv.z += w0 * H0.z + w1 * H1.z + w2 * H2.z + w3 * H3.z
                        + w4 * H4.z + w5 * H5.z + w6 * H6.z + w7 * H7.z;
                accv.w += w0 * H0.w + w1 * H1.w + w2 * H2.w + w3 * H3.w
                        + w4 * H4.w + w5 * H5.w + w6 * H6.w + w7 * H7.w;
                den += ((w0 + w1) + (w2 + w3)) + ((w4 + w5) + (w6 + w7));
            }
            if (j + 4 <= j1) {
                int e0 = srt[j], e1 = srt[j + 1], e2 = srt[j + 2], e3 = srt[j + 3];
                float4 H0 = ldh4(h1, (size_t)e0 * 16 + 4 * q);
                float4 H1 = ldh4(h1, (size_t)e1 * 16 + 4 * q);
                float4 H2 = ldh4(h1, (size_t)e2 * 16 + 4 * q);
                float4 H3 = ldh4(h1, (size_t)e3 * 16 + 4 * q);
                int eq = srt[j + q];
                float wq = __expf(lrelu(s1[eq] + dd) - mb);
                float w0 = __shfl(wq, 0, 4), w1 = __shfl(wq, 1, 4);
                float w2 = __shfl(wq, 2, 4), w3 = __shfl(wq, 3, 4);
                accv.x += w0 * H0.x + w1 * H1.x + w2 * H2.x + w3 * H3.x;
                accv.y += w0 * H0.y + w1 * H1.y + w2 * H2.y + w3 * H3.y;
                accv.z += w0 * H0.z + w1 * H1.z + w2 * H2.z + w3 * H3.z;
                accv.w += w0 * H0.w + w1 * H1.w + w2 * H2.w + w3 * H3.w;
                den += (w0 + w1) + (w2 + w3);
                j += 4;
            }
            for (; j < j1; ++j) {
                int e0 = srt[j];
                float w0 = __expf(lrelu(s1[e0] + dd) - mb);
                float4 H0 = ldh4(h1, (size_t)e0 * 16 + 4 * q);
                accv.x += w0 * H0.x; accv.y += w0 * H0.y;
                accv.z += w0 * H0.z; accv.w += w0 * H0.w;
                den += w0;
            }
        }
        // stage accumulators to LDS (stride-17 rows)
        accs[gg * 17 + 4 * q + 0] = accv.x;
        accs[gg * 17 + 4 * q + 1] = accv.y;
        accs[gg * 17 + 4 * q + 2] = accv.z;
        accs[gg * 17 + 4 * q + 3] = accv.w;
        if (q == 0) accs[gg * 17 + 16] = den;
        __syncthreads();
    } else {
        // overflow: region incomplete -> full rescan of source edges (never-path)
        for (int i = tid; i < BNODES * 17; i += 512) accs[i] = 0.f;
        __syncthreads();
        if (tid < BNODES) {
            int n = node0 + tid;
            if (n < N) {
                float w = __expf(lrelu(s1[n] + dds[tid]) - mbs[tid]);
#pragma unroll
                for (int t = 0; t < 16; ++t)
                    accs[tid * 17 + t] = w * __half2float(h1[(size_t)n * 16 + t]);
                accs[tid * 17 + 16] = w;
            }
        }
        __syncthreads();
        for (int i = tid; i < E; i += 512) {
            int d = edst[i];
            if ((d >> FSH) != fb) continue;
            int nl = d & (BNODES - 1), src = esrc[i];
            float w = __expf(lrelu(s1[src] + dds[nl]) - mbs[nl]);
#pragma unroll
            for (int t = 0; t < 16; ++t)
                atomicAdd(&accs[nl * 17 + t], w * __half2float(h1[(size_t)src * 16 + t]));
            atomicAdd(&accs[nl * 17 + 16], w);
        }
        __syncthreads();
    }

    // epilogue: 32 groups of 16 lanes, 4 nodes each
    int g = tid >> 4, k = tid & 15;
    float sval = -3.4e38f;
#pragma unroll
    for (int qq = 0; qq < 4; ++qq) {
        int nl = g * 4 + qq, nn = node0 + nl;
        if (nn >= N) continue;           // group-uniform
        float inv = 1.f / accs[nl * 17 + 16];
        float o = fmaxf(accs[nl * 17 + k] * inv + sb[k], 0.f);
        float hh = 0.f;
#pragma unroll
        for (int kk = 0; kk < 16; ++kk) {
            float ov = __shfl(o, kk, 16);
            if (k < 10) hh += ov * sW[kk * 10 + k];
        }
        if (k >= 10) hh = 0.f;
        float ts = hh * sas[k];
        float td = hh * sad[k];
#pragma unroll
        for (int off = 1; off < 16; off <<= 1) {
            ts += __shfl_xor(ts, off, 16);
            td += __shfl_xor(td, off, 16);
        }
        h2[(size_t)nn * 16 + k] = __float2half_rn(hh);  // zero-padded cols 10..15
        if (k == 0) { s2[nn] = ts; d2[nn] = td; }
        sval = fmaxf(sval, ts);
    }
    float m = sval;
#pragma unroll
    for (int off = 32; off >= 1; off >>= 1) m = fmaxf(m, __shfl_xor(m, off));
    if ((tid & 63) == 0) wm[tid >> 6] = m;
    __syncthreads();
    if (tid == 0) {
        float bmx = wm[0];
#pragma unroll
        for (int i = 1; i < 8; ++i) bmx = fmaxf(bmx, wm[i]);
        atomicMax(gmax2, fenc(bmx));
    }
}

// ---- layer-2 agg: NO sort — stream agg1's sorted runs + MLP head -> out ----
__global__ __launch_bounds__(512) void k_agg2(
    const int* __restrict__ bcur, const unsigned* __restrict__ pairs,
    const int* __restrict__ nodeofs,
    const int* __restrict__ esrc, const int* __restrict__ edst,
    const float* __restrict__ s2, const float* __restrict__ d2, const __half* __restrict__ h2,
    const float* __restrict__ b2, const float* __restrict__ Wl1, const float* __restrict__ bl1,
    const float* __restrict__ Wl2, const float* __restrict__ bl2,
    const unsigned* __restrict__ gmax2p, float* __restrict__ out, int N, int E)
{
    __shared__ float accs[BNODES * 17];
    __shared__ float dds[BNODES], mbs[BNODES];
    __shared__ float sW1[100], sb1[16], sW2[16], sb2g[16];
    __shared__ float sbl2;

    int tid = threadIdx.x;
    int fb = blockIdx.x;
    if (tid < 100) sW1[tid] = Wl1[tid];
    if (tid < 16) {
        sb1[tid]  = (tid < 10) ? bl1[tid] : 0.f;
        sW2[tid]  = (tid < 10) ? Wl2[tid] : 0.f;
        sb2g[tid] = (tid < 10) ? b2[tid]  : 0.f;
    }
    if (tid == 0) sbl2 = bl2[0];
    int node0 = fb << FSH;
    float g0 = fdec(*gmax2p);
    if (tid < BNODES) {
        int n = node0 + tid;
        float dd = (n < N) ? d2[n] : 0.f;
        dds[tid] = dd; mbs[tid] = lrelu(g0 + dd);
    }
    __syncthreads();

    int rbase = fb * CAPB;
    int cnt = bcur[fb * 16] - rbase;
    int gg = tid >> 2, q = tid & 3;

    if (cnt <= CAPB) {
        const unsigned* gs = pairs + rbase;   // sorted srcs from agg1
        const int* nof = nodeofs + fb * (BNODES + 1);
        int n = node0 + gg;
        float4 accv; float den;
        if (n < N) {
            float w = __expf(lrelu(s2[n] + dds[gg]) - mbs[gg]);
            float4 hv = ldh4(h2, (size_t)n * 16 + 4 * q);   // zero-padded
            accv = make_float4(w * hv.x, w * hv.y, w * hv.z, w * hv.w);
            den = w;
        } else { accv = make_float4(0.f, 0.f, 0.f, 0.f); den = 0.f; }
        {
            float dd = dds[gg], mb = mbs[gg];
            int j = nof[gg], j1 = nof[gg + 1];
            for (; j + 8 <= j1; j += 8) {
                int e0 = gs[j],     e1 = gs[j + 1], e2 = gs[j + 2], e3 = gs[j + 3];
                int e4 = gs[j + 4], e5 = gs[j + 5], e6 = gs[j + 6], e7 = gs[j + 7];
                int eqa = gs[j + q], eqb = gs[j + 4 + q];
                float4 H0 = ldh4(h2, (size_t)e0 * 16 + 4 * q);
                float4 H1 = ldh4(h2, (size_t)e1 * 16 + 4 * q);
                float4 H2 = ldh4(h2, (size_t)e2 * 16 + 4 * q);
                float4 H3 = ldh4(h2, (size_t)e3 * 16 + 4 * q);
                float4 H4 = ldh4(h2, (size_t)e4 * 16 + 4 * q);
                float4 H5 = ldh4(h2, (size_t)e5 * 16 + 4 * q);
                float4 H6 = ldh4(h2, (size_t)e6 * 16 + 4 * q);
                float4 H7 = ldh4(h2, (size_t)e7 * 16 + 4 * q);
                float sA = s2[eqa], sB = s2[eqb];
                float wA = __expf(lrelu(sA + dd) - mb);
                float wB = __expf(lrelu(sB + dd) - mb);
                float w0 = __shfl(wA, 0, 4), w1 = __shfl(wA, 1, 4);
                float w2 = __shfl(wA, 2, 4), w3 = __shfl(wA, 3, 4);
                float w4 = __shfl(wB, 0, 4), w5 = __shfl(wB, 1, 4);
                float w6 = __shfl(wB, 2, 4), w7 = __shfl(wB, 3, 4);
                accv.x += w0 * H0.x + w1 * H1.x + w2 * H2.x + w3 * H3.x
                        + w4 * H4.x + w5 * H5.x + w6 * H6.x + w7 * H7.x;
                accv.y += w0 * H0.y + w1 * H1.y + w2 * H2.y + w3 * H3.y
                        + w4 * H4.y + w5 * H5.y + w6 * H6.y + w7 * H7.y;
                accv.z += w0 * H0.z + w1 * H1.z + w2 * H2.z + w3 * H3.z
                        + w4 * H4.z + w5 * H5.z + w6 * H6.z + w7 * H7.z;
                accv.w += w0 * H0.w + w1 * H1.w + w2 * H2.w + w3 * H3.w
                        + w4 * H4.w + w5 * H5.w + w6 * H6.w + w7 * H7.w;
                den += ((w0 + w1) + (w2 + w3)) + ((w4 + w5) + (w6 + w7));
            }
            if (j + 4 <= j1) {
                int e0 = gs[j], e1 = gs[j + 1], e2 = gs[j + 2], e3 = gs[j + 3];
                float4 H0 = ldh4(h2, (size_t)e0 * 16 + 4 * q);
                float4 H1 = ldh4(h2, (size_t)e1 * 16 + 4 * q);
                float4 H2 = ldh4(h2, (size_t)e2 * 16 + 4 * q);
                float4 H3 = ldh4(h2, (size_t)e3 * 16 + 4 * q);
                int eq = gs[j + q];
                float wq = __expf(lrelu(s2[eq] + dd) - mb);
                float w0 = __shfl(wq, 0, 4), w1 = __shfl(wq, 1, 4);
                float w2 = __shfl(wq, 2, 4), w3 = __shfl(wq, 3, 4);
                accv.x += w0 * H0.x + w1 * H1.x + w2 * H2.x + w3 * H3.x;
                accv.y += w0 * H0.y + w1 * H1.y + w2 * H2.y + w3 * H3.y;
                accv.z += w0 * H0.z + w1 * H1.z + w2 * H2.z + w3 * H3.z;
                accv.w += w0 * H0.w + w1 * H1.w + w2 * H2.w + w3 * H3.w;
                den += (w0 + w1) + (w2 + w3);
                j += 4;
            }
            for (; j < j1; ++j) {
                int e0 = gs[j];
                float w0 = __expf(lrelu(s2[e0] + dd) - mb);
                float4 H0 = ldh4(h2, (size_t)e0 * 16 + 4 * q);
                accv.x += w0 * H0.x; accv.y += w0 * H0.y;
                accv.z += w0 * H0.z; accv.w += w0 * H0.w;
                den += w0;
            }
        }
        accs[gg * 17 + 4 * q + 0] = accv.x;
        accs[gg * 17 + 4 * q + 1] = accv.y;
        accs[gg * 17 + 4 * q + 2] = accv.z;
        accs[gg * 17 + 4 * q + 3] = accv.w;
        if (q == 0) accs[gg * 17 + 16] = den;
        __syncthreads();
    } else {
        // overflow fallback (same condition as agg1; never-path)
        for (int i = tid; i < BNODES * 17; i += 512) accs[i] = 0.f;
        __syncthreads();
        if (tid < BNODES) {
            int n = node0 + tid;
            if (n < N) {
                float w = __expf(lrelu(s2[n] + dds[tid]) - mbs[tid]);
#pragma unroll
                for (int t = 0; t < 16; ++t)
                    accs[tid * 17 + t] = w * __half2float(h2[(size_t)n * 16 + t]);
                accs[tid * 17 + 16] = w;
            }
        }
        __syncthreads();
        for (int i = tid; i < E; i += 512) {
            int d = edst[i];
            if ((d >> FSH) != fb) continue;
            int nl = d & (BNODES - 1), src = esrc[i];
            float w = __expf(lrelu(s2[src] + dds[nl]) - mbs[nl]);
#pragma unroll
            for (int t = 0; t < 16; ++t)
                atomicAdd(&accs[nl * 17 + t], w * __half2float(h2[(size_t)src * 16 + t]));
            atomicAdd(&accs[nl * 17 + 16], w);
        }
        __syncthreads();
    }

    int g = tid >> 4, k = tid & 15;
    bool fk = k < 10;
#pragma unroll
    for (int qq = 0; qq < 4; ++qq) {
        int nl = g * 4 + qq, nn = node0 + nl;
        if (nn >= N) continue;           // group-uniform
        float inv = 1.f / accs[nl * 17 + 16];
        float o = fk ? accs[nl * 17 + k] * inv + sb2g[k] : 0.f;
        float v = sb1[k];
#pragma unroll
        for (int kk = 0; kk < 10; ++kk) {
            float ov = __shfl(o, kk, 16);
            if (fk) v += ov * sW1[kk * 10 + k];
        }
        float t = fmaxf(v, 0.f);
        float cc = t * sW2[k];           // zero for k>=10
#pragma unroll
        for (int off = 1; off < 16; off <<= 1) cc += __shfl_xor(cc, off, 16);
        if (k == 0) out[nn] = cc + sbl2;
    }
}

extern "C" void kernel_launch(void* const* d_in, const int* in_sizes, int n_in,
                              void* d_out, int out_size, void* d_ws, size_t ws_size,
                              hipStream_t stream)
{
    const float* x   = (const float*)d_in[0];
    const int*   ei  = (const int*)  d_in[1];   // [2][E] int32
    const float* W1  = (const float*)d_in[2];
    const float* a1s = (const float*)d_in[3];
    const float* a1d = (const float*)d_in[4];
    const float* b1  = (const float*)d_in[5];
    const float* W2  = (const float*)d_in[6];
    const float* a2s = (const float*)d_in[7];
    const float* a2d = (const float*)d_in[8];
    const float* b2  = (const float*)d_in[9];
    const float* Wl1 = (const float*)d_in[10];
    const float* bl1 = (const float*)d_in[11];
    const float* Wl2 = (const float*)d_in[12];
    const float* bl2 = (const float*)d_in[13];

    int N = in_sizes[0] / 128;
    int E = in_sizes[1] / 2;
    const int* ei_src = ei;
    const int* ei_dst = ei + E;
    int NSB = (N + BNODES - 1) >> FSH;       // 782 buckets (<= NSBMAX)

    size_t Np = ((size_t)N + 3) & ~(size_t)3;
    size_t need_bytes = (16 + Np * 20) * 4 + (size_t)NSB * 16 * 4
                      + (size_t)NSB * CAPB * 4 + (size_t)NSB * (BNODES + 1) * 4;
    if (ws_size < need_bytes) return;  // degrade to wrong-answer, never fault

    float*    ws    = (float*)d_ws;
    unsigned* gmax1 = (unsigned*)d_ws;       // [0]
    unsigned* gmax2 = gmax1 + 1;             // [1]
    __half* h1 = (__half*)(ws + 16);         // Np*16 halves
    float* s1 = ws + 16 + Np * 8;            // Np
    float* d1 = s1 + Np;                     // Np
    __half* h2 = (__half*)(d1 + Np);         // Np*16 halves (cols 10..15 zero)
    float* s2 = (float*)(h2) + Np * 8;       // Np
    float* d2 = s2 + Np;                     // Np
    int* bcur = (int*)(d2 + Np);             // NSB*16 (1 cursor per 64B)
    unsigned* pairs = (unsigned*)(bcur + (size_t)NSB * 16);  // NSB*CAPB
    int* nodeofs = (int*)(pairs + (size_t)NSB * CAPB);       // NSB*(BNODES+1)

    hipLaunchKernelGGL(k_init, dim3((NSB + 255) / 256), dim3(256), 0, stream, gmax1, bcur, NSB);
    hipLaunchKernelGGL(k_gemm1, dim3((N + 63) / 64), dim3(256), 0, stream,
                       x, W1, a1s, a1d, h1, s1, d1, gmax1, N);
    hipLaunchKernelGGL(k_csplit, dim3((E + TILE - 1) / TILE), dim3(512), 0, stream,
                       ei_src, ei_dst, bcur, pairs, E, NSB);
    hipLaunchKernelGGL(k_agg1, dim3(NSB), dim3(512), 0, stream,
                       bcur, pairs, nodeofs, ei_src, ei_dst, s1, d1, h1, b1, W2, a2s, a2d,
                       h2, s2, d2, gmax1, gmax2, N, E);
    hipLaunchKernelGGL(k_agg2, dim3(NSB), dim3(512), 0, stream,
                       bcur, pairs, nodeofs, ei_src, ei_dst, s2, d2, h2, b2, Wl1, bl1, Wl2, bl2,
                       gmax2, (float*)d_out, N, E);
}

// Round 15
// 276.203 us; speedup vs baseline: 1.0959x; 1.0430x over previous
//
#include <hip/hip_runtime.h>
#include <hip/hip_fp16.h>

// GAT (2 layers, heads=1) + 2-layer MLP head. N=100000, E=3200000, D=128.
// R15 = revert to R11 (best measured: 276.4us). 5-kernel pipeline:
// init -> gemm1(fp16 h out) -> csplit(128-node fixed-capacity buckets,
// run-granular flushes) -> agg1 -> agg2 (each: bulk-coalesced pair ingest,
// LDS counting sort, register-accumulated 4-edge gather, fused epilogues).
// Overflow -> full-rescan fallback keeps arbitrary inputs correct.
// Softmax stabilization uses a GLOBAL upper bound m̄_i = leaky(gmax_asrc + adst_i)
// (valid since leaky_relu is monotone); alpha is mathematically unchanged.

#define NEG 0.2f
#define FSH 7
#define BNODES 128           // nodes per bucket
#define NSBMAX 1024          // >= ceil(100000/128)=782
#define CAPB 4608            // per-bucket region capacity (mean 4096, +8 sigma)
#define TILE 8192            // edges per csplit block
#define PES 9                // ceil(CAPB/512) register-staged pairs per thread

__device__ __forceinline__ float lrelu(float x) { return x > 0.0f ? x : NEG * x; }

__device__ __forceinline__ unsigned fenc(float f) {
    unsigned u = __float_as_uint(f);
    return (u & 0x80000000u) ? ~u : (u | 0x80000000u);
}
__device__ __forceinline__ float fdec(unsigned e) {
    return (e & 0x80000000u) ? __uint_as_float(e & 0x7FFFFFFFu) : __uint_as_float(~e);
}

// load 4 consecutive halves as float4 (8B load)
__device__ __forceinline__ float4 ldh4(const __half* h, size_t off) {
    uint2 u = *(const uint2*)(h + off);
    __half2 a = *(__half2*)&u.x, b = *(__half2*)&u.y;
    float2 fa = __half22float2(a), fb = __half22float2(b);
    return make_float4(fa.x, fa.y, fb.x, fb.y);
}

// init gmax + per-bucket region cursors (absolute positions)
__global__ __launch_bounds__(256) void k_init(unsigned* g, int* bcur, int NSB) {
    int i = blockIdx.x * 256 + threadIdx.x;
    if (i < NSB) bcur[i * 16] = i * CAPB;
    if (i < 2) g[i] = 0u;
}

// K1: h1 = x @ W1 (128->16) [fp16 out], s1 = h1·a1s, d1 = h1·a1d, gmax1 = max(s1)
__global__ __launch_bounds__(256) void k_gemm1(
    const float* __restrict__ x, const float* __restrict__ W1,
    const float* __restrict__ a1s, const float* __restrict__ a1d,
    __half* __restrict__ h1, float* __restrict__ s1, float* __restrict__ d1,
    unsigned* __restrict__ gmax, int N)
{
    __shared__ float sW[128 * 16];
    __shared__ float sx[64 * 132];
    __shared__ float wm[4];
    int tid = threadIdx.x;
    for (int i = tid; i < 2048; i += 256) sW[i] = W1[i];
    int node0 = blockIdx.x * 64;
    for (int i = tid; i < 64 * 32; i += 256) {
        int row = i >> 5, c4 = i & 31;
        int n = node0 + row;
        float4 v = make_float4(0.f, 0.f, 0.f, 0.f);
        if (n < N) v = ((const float4*)x)[(size_t)n * 32 + c4];
        *(float4*)&sx[row * 132 + c4 * 4] = v;
    }
    __syncthreads();

    int node = node0 + (tid >> 2);
    int grp  = tid & 3;
    const float* xr = &sx[(tid >> 2) * 132];
    float4 acc = make_float4(0.f, 0.f, 0.f, 0.f);
#pragma unroll 8
    for (int j = 0; j < 128; ++j) {
        float xv = xr[j];
        float4 w = *(const float4*)&sW[j * 16 + grp * 4];
        acc.x += xv * w.x; acc.y += xv * w.y; acc.z += xv * w.z; acc.w += xv * w.w;
    }
    float4 as = ((const float4*)a1s)[grp];
    float4 ad = ((const float4*)a1d)[grp];
    float sv = acc.x * as.x + acc.y * as.y + acc.z * as.z + acc.w * as.w;
    float dv = acc.x * ad.x + acc.y * ad.y + acc.z * ad.z + acc.w * ad.w;
    sv += __shfl_xor(sv, 1); sv += __shfl_xor(sv, 2);
    dv += __shfl_xor(dv, 1); dv += __shfl_xor(dv, 2);
    if (node < N) {
        __half2 p0 = __floats2half2_rn(acc.x, acc.y);
        __half2 p1 = __floats2half2_rn(acc.z, acc.w);
        uint2 u; u.x = *(unsigned*)&p0; u.y = *(unsigned*)&p1;
        *(uint2*)&h1[(size_t)node * 16 + grp * 4] = u;
        if (grp == 0) { s1[node] = sv; d1[node] = dv; }
    }
    float m = (node < N) ? sv : -3.4e38f;
#pragma unroll
    for (int off = 32; off >= 1; off >>= 1) m = fmaxf(m, __shfl_xor(m, off));
    if ((tid & 63) == 0) wm[tid >> 6] = m;
    __syncthreads();
    if (tid == 0) {
        float b = fmaxf(fmaxf(wm[0], wm[1]), fmaxf(wm[2], wm[3]));
        atomicMax(gmax, fenc(b));
    }
}

// split: LDS-sort a tile of 8192 edges by 128-node bucket, flush run-granular
// into fixed per-bucket regions; elements past a region's limit are dropped
// (bucket flagged by cursor > limit; agg rescans such buckets from the source).
__global__ __launch_bounds__(512) void k_csplit(
    const int* __restrict__ esrc, const int* __restrict__ edst,
    int* __restrict__ bcur, unsigned* __restrict__ pairs, int E, int NSB)
{
    __shared__ unsigned lsrt[TILE];
    __shared__ int lhist[NSBMAX];        // counts -> cursors
    __shared__ int lofs[NSBMAX];         // exclusive run starts
    __shared__ int gbase[NSBMAX];
    __shared__ int wsum[8];
    int tid = threadIdx.x;
    int base = blockIdx.x * TILE;
    int tcnt = min(TILE, E - base);
    for (int i = tid; i < NSB; i += 512) lhist[i] = 0;
    __syncthreads();
    for (int i = tid; i < tcnt; i += 512)
        atomicAdd(&lhist[edst[base + i] >> FSH], 1);
    __syncthreads();
    int i0 = 2 * tid, i1 = i0 + 1;
    int a = (i0 < NSB) ? lhist[i0] : 0;
    int b = (i1 < NSB) ? lhist[i1] : 0;
    int s = a + b, pfx = s;
#pragma unroll
    for (int off = 1; off < 64; off <<= 1) {
        int t = __shfl_up(pfx, off, 64);
        if ((tid & 63) >= off) pfx += t;
    }
    if ((tid & 63) == 63) wsum[tid >> 6] = pfx;
    __syncthreads();
    int carry = 0;
    for (int w = 0; w < (tid >> 6); ++w) carry += wsum[w];
    int excl = pfx + carry - s;
    if (i0 < NSB) {
        lofs[i0] = excl;
        gbase[i0] = a ? atomicAdd(&bcur[i0 * 16], a) : 0;
    }
    if (i1 < NSB) {
        lofs[i1] = excl + a;
        gbase[i1] = b ? atomicAdd(&bcur[i1 * 16], b) : 0;
    }
    __syncthreads();
    if (i0 < NSB) lhist[i0] = lofs[i0];  // cursors
    if (i1 < NSB) lhist[i1] = lofs[i1];
    __syncthreads();
    for (int i = tid; i < tcnt; i += 512) {
        int e = base + i;
        int d = edst[e], srcv = esrc[e];
        int pos = atomicAdd(&lhist[d >> FSH], 1);
        lsrt[pos] = ((unsigned)(d & (BNODES - 1)) << 17) | (unsigned)srcv;
    }
    __syncthreads();
    // flattened flush: binary search run id, coalesced run-contiguous stores
    for (int i = tid; i < tcnt; i += 512) {
        int lo = 0, hi = NSB - 1;
        while (lo < hi) { int mid = (lo + hi + 1) >> 1; if (lofs[mid] <= i) lo = mid; else hi = mid - 1; }
        int gp = gbase[lo] + (i - lofs[lo]);
        if (gp < (lo + 1) * CAPB) pairs[gp] = lsrt[i];
    }
}

// ---- layer-1 agg: own-region LDS sort + shared-exp 4-lane fp16 gather ----
__global__ __launch_bounds__(512) void k_agg1(
    const int* __restrict__ bcur, const unsigned* __restrict__ pairs,
    const int* __restrict__ esrc, const int* __restrict__ edst,
    const float* __restrict__ s1, const float* __restrict__ d1, const __half* __restrict__ h1,
    const float* __restrict__ b1, const float* __restrict__ W2,
    const float* __restrict__ a2s, const float* __restrict__ a2d,
    __half* __restrict__ h2, float* __restrict__ s2, float* __restrict__ d2,
    const unsigned* __restrict__ gmax1p, unsigned* __restrict__ gmax2, int N, int E)
{
    __shared__ unsigned srt[CAPB];
    __shared__ float accs[BNODES * 17];
    __shared__ int lcnt[BNODES];
    __shared__ int lofs[BNODES + 1];
    __shared__ float dds[BNODES], mbs[BNODES];
    __shared__ float sW[160], sb[16], sas[16], sad[16];
    __shared__ int wsum[8];
    __shared__ float wm[8];

    int tid = threadIdx.x;
    int fb = blockIdx.x;
    if (tid < 160) sW[tid] = W2[tid];
    if (tid < 16) {
        sb[tid]  = b1[tid];
        sas[tid] = (tid < 10) ? a2s[tid] : 0.f;
        sad[tid] = (tid < 10) ? a2d[tid] : 0.f;
    }
    int node0 = fb << FSH;
    float g0 = fdec(*gmax1p);
    if (tid < BNODES) {
        int n = node0 + tid;
        float dd = (n < N) ? d1[n] : 0.f;
        dds[tid] = dd; mbs[tid] = lrelu(g0 + dd);
        lcnt[tid] = 0;
    }
    __syncthreads();

    int rbase = fb * CAPB;
    int cnt = bcur[fb * 16] - rbase;     // block-uniform; > CAPB means overflow
    int gg = tid >> 2, q = tid & 3;      // 128 groups x 4 lanes, 1 node each

    if (cnt <= CAPB) {
        // count pass with register staging (single global read of pairs)
        unsigned pe[PES];
#pragma unroll
        for (int u = 0; u < PES; ++u) {
            int i = tid + u * 512;
            bool ok = (i < cnt);
            pe[u] = ok ? pairs[rbase + i] : 0u;
            if (ok) atomicAdd(&lcnt[(pe[u] >> 17) & (BNODES - 1)], 1);
        }
        __syncthreads();
        // 128-key scan (padded to 512 threads)
        int c = (tid < BNODES) ? lcnt[tid] : 0;
        int pfx = c;
#pragma unroll
        for (int off = 1; off < 64; off <<= 1) {
            int t = __shfl_up(pfx, off, 64);
            if ((tid & 63) >= off) pfx += t;
        }
        if ((tid & 63) == 63) wsum[tid >> 6] = pfx;
        __syncthreads();
        int carry = 0;
        for (int w = 0; w < (tid >> 6); ++w) carry += wsum[w];
        pfx += carry;
        if (tid < BNODES) { lofs[tid + 1] = pfx; lcnt[tid] = pfx - c; }
        if (tid == 0) lofs[0] = 0;
        __syncthreads();
        // scatter pass from registers -> dst-sorted srcs
#pragma unroll
        for (int u = 0; u < PES; ++u) {
            int i = tid + u * 512;
            if (i < cnt) {
                unsigned p = pe[u];
                int pos = atomicAdd(&lcnt[(p >> 17) & (BNODES - 1)], 1);
                srt[pos] = p & 0x1FFFF;
            }
        }
        __syncthreads();

        // self-loop init + register gather (1 exp/edge via width-4 shfl)
        int n = node0 + gg;
        float4 accv; float den;
        if (n < N) {
            float w = __expf(lrelu(s1[n] + dds[gg]) - mbs[gg]);
            float4 hv = ldh4(h1, (size_t)n * 16 + 4 * q);
            accv = make_float4(w * hv.x, w * hv.y, w * hv.z, w * hv.w);
            den = w;
        } else { accv = make_float4(0.f, 0.f, 0.f, 0.f); den = 0.f; }
        {
            float dd = dds[gg], mb = mbs[gg];
            int j = lofs[gg], j1 = lofs[gg + 1];
            for (; j + 4 <= j1; j += 4) {
                int e0 = srt[j], e1 = srt[j + 1], e2 = srt[j + 2], e3 = srt[j + 3];
                float4 H0 = ldh4(h1, (size_t)e0 * 16 + 4 * q);
                float4 H1 = ldh4(h1, (size_t)e1 * 16 + 4 * q);
                float4 H2 = ldh4(h1, (size_t)e2 * 16 + 4 * q);
                float4 H3 = ldh4(h1, (size_t)e3 * 16 + 4 * q);
                int eq = srt[j + q];
                float wq = __expf(lrelu(s1[eq] + dd) - mb);
                float w0 = __shfl(wq, 0, 4), w1 = __shfl(wq, 1, 4);
                float w2 = __shfl(wq, 2, 4), w3 = __shfl(wq, 3, 4);
                accv.x += w0 * H0.x + w1 * H1.x + w2 * H2.x + w3 * H3.x;
                accv.y += w0 * H0.y + w1 * H1.y + w2 * H2.y + w3 * H3.y;
                accv.z += w0 * H0.z + w1 * H1.z + w2 * H2.z + w3 * H3.z;
                accv.w += w0 * H0.w + w1 * H1.w + w2 * H2.w + w3 * H3.w;
                den += (w0 + w1) + (w2 + w3);
            }
            for (; j < j1; ++j) {
                int e0 = srt[j];
                float w0 = __expf(lrelu(s1[e0] + dd) - mb);
                float4 H0 = ldh4(h1, (size_t)e0 * 16 + 4 * q);
                accv.x += w0 * H0.x; accv.y += w0 * H0.y;
                accv.z += w0 * H0.z; accv.w += w0 * H0.w;
                den += w0;
            }
        }
        // stage accumulators to LDS (stride-17 rows)
        accs[gg * 17 + 4 * q + 0] = accv.x;
        accs[gg * 17 + 4 * q + 1] = accv.y;
        accs[gg * 17 + 4 * q + 2] = accv.z;
        accs[gg * 17 + 4 * q + 3] = accv.w;
        if (q == 0) accs[gg * 17 + 16] = den;
        __syncthreads();
    } else {
        // overflow: region incomplete -> full rescan of source edges (never-path)
        for (int i = tid; i < BNODES * 17; i += 512) accs[i] = 0.f;
        __syncthreads();
        if (tid < BNODES) {
            int n = node0 + tid;
            if (n < N) {
                float w = __expf(lrelu(s1[n] + dds[tid]) - mbs[tid]);
#pragma unroll
                for (int t = 0; t < 16; ++t)
                    accs[tid * 17 + t] = w * __half2float(h1[(size_t)n * 16 + t]);
                accs[tid * 17 + 16] = w;
            }
        }
        __syncthreads();
        for (int i = tid; i < E; i += 512) {
            int d = edst[i];
            if ((d >> FSH) != fb) continue;
            int nl = d & (BNODES - 1), src = esrc[i];
            float w = __expf(lrelu(s1[src] + dds[nl]) - mbs[nl]);
#pragma unroll
            for (int t = 0; t < 16; ++t)
                atomicAdd(&accs[nl * 17 + t], w * __half2float(h1[(size_t)src * 16 + t]));
            atomicAdd(&accs[nl * 17 + 16], w);
        }
        __syncthreads();
    }

    // epilogue: 32 groups of 16 lanes, 4 nodes each
    int g = tid >> 4, k = tid & 15;
    float sval = -3.4e38f;
#pragma unroll
    for (int qq = 0; qq < 4; ++qq) {
        int nl = g * 4 + qq, nn = node0 + nl;
        if (nn >= N) continue;           // group-uniform
        float inv = 1.f / accs[nl * 17 + 16];
        float o = fmaxf(accs[nl * 17 + k] * inv + sb[k], 0.f);
        float hh = 0.f;
#pragma unroll
        for (int kk = 0; kk < 16; ++kk) {
            float ov = __shfl(o, kk, 16);
            if (k < 10) hh += ov * sW[kk * 10 + k];
        }
        if (k >= 10) hh = 0.f;
        float ts = hh * sas[k];
        float td = hh * sad[k];
#pragma unroll
        for (int off = 1; off < 16; off <<= 1) {
            ts += __shfl_xor(ts, off, 16);
            td += __shfl_xor(td, off, 16);
        }
        h2[(size_t)nn * 16 + k] = __float2half_rn(hh);  // zero-padded cols 10..15
        if (k == 0) { s2[nn] = ts; d2[nn] = td; }
        sval = fmaxf(sval, ts);
    }
    float m = sval;
#pragma unroll
    for (int off = 32; off >= 1; off >>= 1) m = fmaxf(m, __shfl_xor(m, off));
    if ((tid & 63) == 0) wm[tid >> 6] = m;
    __syncthreads();
    if (tid == 0) {
        float bmx = wm[0];
#pragma unroll
        for (int i = 1; i < 8; ++i) bmx = fmaxf(bmx, wm[i]);
        atomicMax(gmax2, fenc(bmx));
    }
}

// ---- layer-2 agg (same structure) + norm/bias + MLP head -> out ----
__global__ __launch_bounds__(512) void k_agg2(
    const int* __restrict__ bcur, const unsigned* __restrict__ pairs,
    const int* __restrict__ esrc, const int* __restrict__ edst,
    const float* __restrict__ s2, const float* __restrict__ d2, const __half* __restrict__ h2,
    const float* __restrict__ b2, const float* __restrict__ Wl1, const float* __restrict__ bl1,
    const float* __restrict__ Wl2, const float* __restrict__ bl2,
    const unsigned* __restrict__ gmax2p, float* __restrict__ out, int N, int E)
{
    __shared__ unsigned srt[CAPB];
    __shared__ float accs[BNODES * 17];
    __shared__ int lcnt[BNODES];
    __shared__ int lofs[BNODES + 1];
    __shared__ float dds[BNODES], mbs[BNODES];
    __shared__ float sW1[100], sb1[16], sW2[16], sb2g[16];
    __shared__ float sbl2;
    __shared__ int wsum[8];

    int tid = threadIdx.x;
    int fb = blockIdx.x;
    if (tid < 100) sW1[tid] = Wl1[tid];
    if (tid < 16) {
        sb1[tid]  = (tid < 10) ? bl1[tid] : 0.f;
        sW2[tid]  = (tid < 10) ? Wl2[tid] : 0.f;
        sb2g[tid] = (tid < 10) ? b2[tid]  : 0.f;
    }
    if (tid == 0) sbl2 = bl2[0];
    int node0 = fb << FSH;
    float g0 = fdec(*gmax2p);
    if (tid < BNODES) {
        int n = node0 + tid;
        float dd = (n < N) ? d2[n] : 0.f;
        dds[tid] = dd; mbs[tid] = lrelu(g0 + dd);
        lcnt[tid] = 0;
    }
    __syncthreads();

    int rbase = fb * CAPB;
    int cnt = bcur[fb * 16] - rbase;
    int gg = tid >> 2, q = tid & 3;

    if (cnt <= CAPB) {
        unsigned pe[PES];
#pragma unroll
        for (int u = 0; u < PES; ++u) {
            int i = tid + u * 512;
            bool ok = (i < cnt);
            pe[u] = ok ? pairs[rbase + i] : 0u;
            if (ok) atomicAdd(&lcnt[(pe[u] >> 17) & (BNODES - 1)], 1);
        }
        __syncthreads();
        int c = (tid < BNODES) ? lcnt[tid] : 0;
        int pfx = c;
#pragma unroll
        for (int off = 1; off < 64; off <<= 1) {
            int t = __shfl_up(pfx, off, 64);
            if ((tid & 63) >= off) pfx += t;
        }
        if ((tid & 63) == 63) wsum[tid >> 6] = pfx;
        __syncthreads();
        int carry = 0;
        for (int w = 0; w < (tid >> 6); ++w) carry += wsum[w];
        pfx += carry;
        if (tid < BNODES) { lofs[tid + 1] = pfx; lcnt[tid] = pfx - c; }
        if (tid == 0) lofs[0] = 0;
        __syncthreads();
#pragma unroll
        for (int u = 0; u < PES; ++u) {
            int i = tid + u * 512;
            if (i < cnt) {
                unsigned p = pe[u];
                int pos = atomicAdd(&lcnt[(p >> 17) & (BNODES - 1)], 1);
                srt[pos] = p & 0x1FFFF;
            }
        }
        __syncthreads();

        int n = node0 + gg;
        float4 accv; float den;
        if (n < N) {
            float w = __expf(lrelu(s2[n] + dds[gg]) - mbs[gg]);
            float4 hv = ldh4(h2, (size_t)n * 16 + 4 * q);   // zero-padded
            accv = make_float4(w * hv.x, w * hv.y, w * hv.z, w * hv.w);
            den = w;
        } else { accv = make_float4(0.f, 0.f, 0.f, 0.f); den = 0.f; }
        {
            float dd = dds[gg], mb = mbs[gg];
            int j = lofs[gg], j1 = lofs[gg + 1];
            for (; j + 4 <= j1; j += 4) {
                int e0 = srt[j], e1 = srt[j + 1], e2 = srt[j + 2], e3 = srt[j + 3];
                float4 H0 = ldh4(h2, (size_t)e0 * 16 + 4 * q);
                float4 H1 = ldh4(h2, (size_t)e1 * 16 + 4 * q);
                float4 H2 = ldh4(h2, (size_t)e2 * 16 + 4 * q);
                float4 H3 = ldh4(h2, (size_t)e3 * 16 + 4 * q);
                int eq = srt[j + q];
                float wq = __expf(lrelu(s2[eq] + dd) - mb);
                float w0 = __shfl(wq, 0, 4), w1 = __shfl(wq, 1, 4);
                float w2 = __shfl(wq, 2, 4), w3 = __shfl(wq, 3, 4);
                accv.x += w0 * H0.x + w1 * H1.x + w2 * H2.x + w3 * H3.x;
                accv.y += w0 * H0.y + w1 * H1.y + w2 * H2.y + w3 * H3.y;
                accv.z += w0 * H0.z + w1 * H1.z + w2 * H2.z + w3 * H3.z;
                accv.w += w0 * H0.w + w1 * H1.w + w2 * H2.w + w3 * H3.w;
                den += (w0 + w1) + (w2 + w3);
            }
            for (; j < j1; ++j) {
                int e0 = srt[j];
                float w0 = __expf(lrelu(s2[e0] + dd) - mb);
                float4 H0 = ldh4(h2, (size_t)e0 * 16 + 4 * q);
                accv.x += w0 * H0.x; accv.y += w0 * H0.y;
                accv.z += w0 * H0.z; accv.w += w0 * H0.w;
                den += w0;
            }
        }
        accs[gg * 17 + 4 * q + 0] = accv.x;
        accs[gg * 17 + 4 * q + 1] = accv.y;
        accs[gg * 17 + 4 * q + 2] = accv.z;
        accs[gg * 17 + 4 * q + 3] = accv.w;
        if (q == 0) accs[gg * 17 + 16] = den;
        __syncthreads();
    } else {
        for (int i = tid; i < BNODES * 17; i += 512) accs[i] = 0.f;
        __syncthreads();
        if (tid < BNODES) {
            int n = node0 + tid;
            if (n < N) {
                float w = __expf(lrelu(s2[n] + dds[tid]) - mbs[tid]);
#pragma unroll
                for (int t = 0; t < 16; ++t)
                    accs[tid * 17 + t] = w * __half2float(h2[(size_t)n * 16 + t]);
                accs[tid * 17 + 16] = w;
            }
        }
        __syncthreads();
        for (int i = tid; i < E; i += 512) {
            int d = edst[i];
            if ((d >> FSH) != fb) continue;
            int nl = d & (BNODES - 1), src = esrc[i];
            float w = __expf(lrelu(s2[src] + dds[nl]) - mbs[nl]);
#pragma unroll
            for (int t = 0; t < 16; ++t)
                atomicAdd(&accs[nl * 17 + t], w * __half2float(h2[(size_t)src * 16 + t]));
            atomicAdd(&accs[nl * 17 + 16], w);
        }
        __syncthreads();
    }

    int g = tid >> 4, k = tid & 15;
    bool fk = k < 10;
#pragma unroll
    for (int qq = 0; qq < 4; ++qq) {
        int nl = g * 4 + qq, nn = node0 + nl;
        if (nn >= N) continue;           // group-uniform
        float inv = 1.f / accs[nl * 17 + 16];
        float o = fk ? accs[nl * 17 + k] * inv + sb2g[k] : 0.f;
        float v = sb1[k];
#pragma unroll
        for (int kk = 0; kk < 10; ++kk) {
            float ov = __shfl(o, kk, 16);
            if (fk) v += ov * sW1[kk * 10 + k];
        }
        float t = fmaxf(v, 0.f);
        float cc = t * sW2[k];           // zero for k>=10
#pragma unroll
        for (int off = 1; off < 16; off <<= 1) cc += __shfl_xor(cc, off, 16);
        if (k == 0) out[nn] = cc + sbl2;
    }
}

extern "C" void kernel_launch(void* const* d_in, const int* in_sizes, int n_in,
                              void* d_out, int out_size, void* d_ws, size_t ws_size,
                              hipStream_t stream)
{
    const float* x   = (const float*)d_in[0];
    const int*   ei  = (const int*)  d_in[1];   // [2][E] int32
    const float* W1  = (const float*)d_in[2];
    const float* a1s = (const float*)d_in[3];
    const float* a1d = (const float*)d_in[4];
    const float* b1  = (const float*)d_in[5];
    const float* W2  = (const float*)d_in[6];
    const float* a2s = (const float*)d_in[7];
    const float* a2d = (const float*)d_in[8];
    const float* b2  = (const float*)d_in[9];
    const float* Wl1 = (const float*)d_in[10];
    const float* bl1 = (const float*)d_in[11];
    const float* Wl2 = (const float*)d_in[12];
    const float* bl2 = (const float*)d_in[13];

    int N = in_sizes[0] / 128;
    int E = in_sizes[1] / 2;
    const int* ei_src = ei;
    const int* ei_dst = ei + E;
    int NSB = (N + BNODES - 1) >> FSH;       // 782 buckets (<= NSBMAX)

    size_t Np = ((size_t)N + 3) & ~(size_t)3;
    size_t need_bytes = (16 + Np * 20) * 4 + (size_t)NSB * 16 * 4 + (size_t)NSB * CAPB * 4;
    if (ws_size < need_bytes) return;  // degrade to wrong-answer, never fault

    float*    ws    = (float*)d_ws;
    unsigned* gmax1 = (unsigned*)d_ws;       // [0]
    unsigned* gmax2 = gmax1 + 1;             // [1]
    __half* h1 = (__half*)(ws + 16);         // Np*16 halves
    float* s1 = ws + 16 + Np * 8;            // Np
    float* d1 = s1 + Np;                     // Np
    __half* h2 = (__half*)(d1 + Np);         // Np*16 halves (cols 10..15 zero)
    float* s2 = (float*)(h2) + Np * 8;       // Np
    float* d2 = s2 + Np;                     // Np
    int* bcur = (int*)(d2 + Np);             // NSB*16 (1 cursor per 64B)
    unsigned* pairs = (unsigned*)(bcur + (size_t)NSB * 16);  // NSB*CAPB

    hipLaunchKernelGGL(k_init, dim3((NSB + 255) / 256), dim3(256), 0, stream, gmax1, bcur, NSB);
    hipLaunchKernelGGL(k_gemm1, dim3((N + 63) / 64), dim3(256), 0, stream,
                       x, W1, a1s, a1d, h1, s1, d1, gmax1, N);
    hipLaunchKernelGGL(k_csplit, dim3((E + TILE - 1) / TILE), dim3(512), 0, stream,
                       ei_src, ei_dst, bcur, pairs, E, NSB);
    hipLaunchKernelGGL(k_agg1, dim3(NSB), dim3(512), 0, stream,
                       bcur, pairs, ei_src, ei_dst, s1, d1, h1, b1, W2, a2s, a2d,
                       h2, s2, d2, gmax1, gmax2, N, E);
    hipLaunchKernelGGL(k_agg2, dim3(NSB), dim3(512), 0, stream,
                       bcur, pairs, ei_src, ei_dst, s2, d2, h2, b2, Wl1, bl1, Wl2, bl2,
                       gmax2, (float*)d_out, N, E);
}